// Round 10
// baseline (189.341 us; speedup 1.0000x reference)
//
#include <hip/hip_runtime.h>
#include <stdint.h>

typedef unsigned short u16;
typedef __attribute__((ext_vector_type(8))) short short8;
typedef __attribute__((ext_vector_type(4))) float floatx4;
typedef __attribute__((ext_vector_type(4))) u16 ushort4v;

typedef __attribute__((address_space(1))) const uint32_t gu32;
typedef __attribute__((address_space(3))) uint32_t lu32;

#define MFMA(a, b, c) __builtin_amdgcn_mfma_f32_16x16x32_bf16((a), (b), (c), 0, 0, 0)

__device__ __forceinline__ u16 f2bf(float f) {
    union { float f; uint32_t u; } x; x.f = f;
    uint32_t u = x.u;
    u += 0x7fffu + ((u >> 16) & 1u);
    return (u16)(u >> 16);
}

// packed f32x2 -> bf16x2 (RNE), single instruction (T12 primitive)
__device__ __forceinline__ uint32_t cvtpk_bf16(float lo, float hi) {
    uint32_t r;
    asm("v_cvt_pk_bf16_f32 %0, %1, %2" : "=v"(r) : "v"(lo), "v"(hi));
    return r;
}

// hardware exp2 (v_exp_f32 IS exp2)
__device__ __forceinline__ float fexp2(float x) {
#if defined(__has_builtin)
#if __has_builtin(__builtin_amdgcn_exp2f)
    return __builtin_amdgcn_exp2f(x);
#else
    return exp2f(x);
#endif
#else
    return exp2f(x);
#endif
}

// async global->LDS DMA, 16B per lane; lds base must be wave-uniform,
// HW scatters to base + lane*16 (m104/m108).
__device__ __forceinline__ void async16(u16* lds, const u16* g) {
    __builtin_amdgcn_global_load_lds((gu32*)g, (lu32*)lds, 16, 0, 0);
}

// K/V LDS tiles (attn): [64 rows][128 B], XOR-swizzled: byte ^= (row&7)<<4.
#define KV8(buf, row, byteInRow) \
    (*(short8*)((char*)(buf) + (((row) << 7) + ((byteInRow) ^ (((row) & 7) << 4)))))

// 0.125 (1/sqrt(64)) * log2(e): folded into Q so softmax runs in exp2 domain.
#define Q_SCALE_LOG2E 0.18033688011112042f

// ---------------------------------------------------------------------------
// prep: z=0..3 transpose W_z [k][n] fp32 -> WT [n][k] bf16; z=4 convert x.
// ---------------------------------------------------------------------------
__global__ __launch_bounds__(256) void prep_kernel(
    const float* __restrict__ x,
    const float* __restrict__ W0, const float* __restrict__ W1,
    const float* __restrict__ W2, const float* __restrict__ W3,
    u16* __restrict__ WT, u16* __restrict__ Xbf)
{
    const int z = blockIdx.z;
    const int tx = threadIdx.x, ty = threadIdx.y;
    if (z == 4) {
        const int bid = blockIdx.y * 32 + blockIdx.x;
        const int t = ty * 32 + tx;
        const size_t base = ((size_t)bid * 256 + t) * 16;
        const float* xf = x + base;
        short8 v0, v1;
#pragma unroll
        for (int j = 0; j < 8; j++) v0[j] = (short)f2bf(xf[j]);
#pragma unroll
        for (int j = 0; j < 8; j++) v1[j] = (short)f2bf(xf[8 + j]);
        *(short8*)&Xbf[base] = v0;
        *(short8*)&Xbf[base + 8] = v1;
        return;
    }
    __shared__ u16 tile[32][33];
    const float* W = (z == 0) ? W0 : (z == 1) ? W1 : (z == 2) ? W2 : W3;
    u16* dst = WT + (size_t)z * 1024 * 1024;
    const int n0 = blockIdx.x * 32, k0 = blockIdx.y * 32;
#pragma unroll
    for (int i = 0; i < 4; i++)
        tile[ty + i * 8][tx] = f2bf(W[(size_t)(k0 + ty + i * 8) * 1024 + n0 + tx]);
    __syncthreads();
#pragma unroll
    for (int i = 0; i < 4; i++)
        dst[(size_t)(n0 + ty + i * 8) * 1024 + k0 + tx] = tile[tx][ty + i * 8];
}

// ---------------------------------------------------------------------------
// GEMM core (round-6, verified 44.3 us): BK=64 / 128x128 tile / 4 waves /
// single 32-KB LDS buffer, swizzled (inverse-swizzled source + XOR'd read).
// ---------------------------------------------------------------------------
#define GSTAGE64(buf, gptr, kk) do { \
    _Pragma("unroll") \
    for (int i_ = 0; i_ < 4; i_++) \
        async16((buf) + wave * 512 + i_ * 2048, (gptr) + (kk) + (size_t)i_ * 32 * 1024); \
} while (0)

// frag read: row = base + fr*16 + lrow (row&7 == lrow&7); granule g = ks*4+lquad
#define GFRAG64(buf, base, ks, fr) \
    (*(const short8*)&(buf)[((base) + (fr) * 16 + lrow) * 64 + ((((ks) * 4 + lquad) ^ (lrow & 7)) * 8)])

#define GCOMPUTE64() do { \
    _Pragma("unroll") \
    for (int ks = 0; ks < 2; ks++) { \
        short8 af[4], bfv[4]; \
        _Pragma("unroll") \
        for (int mt = 0; mt < 4; mt++) af[mt] = GFRAG64(As, wr, ks, mt); \
        _Pragma("unroll") \
        for (int nt = 0; nt < 4; nt++) bfv[nt] = GFRAG64(Bs, wc, ks, nt); \
        _Pragma("unroll") \
        for (int mt = 0; mt < 4; mt++) \
            _Pragma("unroll") \
            for (int nt = 0; nt < 4; nt++) \
                acc[mt][nt] = MFMA(af[mt], bfv[nt], acc[mt][nt]); \
    } \
} while (0)

#define GEMM_K_LOOP64() do { \
    for (int kk = 0; kk < 1024; kk += 64) { \
        __syncthreads(); \
        GSTAGE64(As, gA, kk); \
        GSTAGE64(Bs, gB, kk); \
        __syncthreads(); \
        GCOMPUTE64(); \
    } \
} while (0)

// ---------------------------------------------------------------------------
// QKV GEMM: 768 blocks (xcd-striped), BK=64 structure above.
// Q outputs pre-scaled by 0.125*log2e (softmax runs in exp2 domain).
// ---------------------------------------------------------------------------
__global__ __launch_bounds__(256) void gemm_qkv_kernel(
    const u16* __restrict__ X, const u16* __restrict__ WT,
    u16* __restrict__ Q, u16* __restrict__ Kout, u16* __restrict__ VT)
{
    __shared__ __align__(16) u16 As[128 * 64];
    __shared__ __align__(16) u16 Bs[128 * 64];
    const int bid = blockIdx.x;
    const int xcd = bid & 7;
    const int idx = bid >> 3;          // 0..95
    const int mat = idx >> 5;          // 0..2
    const int rr  = (idx >> 3) & 3;    // 0..3
    const int nn  = idx & 7;           // 0..7
    const int m0 = (xcd * 4 + rr) * 128;
    const int n0 = nn * 128;
    const u16* BW = WT + (size_t)mat * 1024 * 1024;
    const int tid = threadIdx.x;
    const int wave = tid >> 6, lane = tid & 63;
    const int lrow = lane & 15, lquad = lane >> 4;
    const int wr = (wave >> 1) * 64, wc = (wave & 1) * 64;

    const int stg_r = tid >> 3;                                  // 0..31
    const int stg_c = ((tid & 7) ^ ((tid >> 3) & 7)) * 8;        // inv-swizzled col
    const u16* gA = &X[(size_t)(m0 + stg_r) * 1024 + stg_c];
    const u16* gB = &BW[(size_t)(n0 + stg_r) * 1024 + stg_c];

    floatx4 acc[4][4];
#pragma unroll
    for (int mt = 0; mt < 4; mt++)
#pragma unroll
        for (int nt = 0; nt < 4; nt++) acc[mt][nt] = (floatx4){0.f, 0.f, 0.f, 0.f};

    GEMM_K_LOOP64();

    const float qs = (mat == 0) ? Q_SCALE_LOG2E : 1.0f;
#pragma unroll
    for (int mt = 0; mt < 4; mt++) {
        const int gm = m0 + wr + mt * 16 + lquad * 4;
        const int b_ = gm >> 11;
        const int s  = gm & 2047;
#pragma unroll
        for (int nt = 0; nt < 4; nt++) {
            const int gn = n0 + wc + nt * 16 + lrow;
            const int h = gn >> 6, hd = gn & 63;
            const int bh = b_ * 16 + h;
            if (mat == 2) {
                ushort4v v;
#pragma unroll
                for (int i = 0; i < 4; i++) v[i] = f2bf(acc[mt][nt][i]);
                *(ushort4v*)&VT[((size_t)bh * 64 + hd) * 2048 + s] = v;
            } else {
                u16* dst = (mat == 0) ? Q : Kout;
#pragma unroll
                for (int i = 0; i < 4; i++)
                    dst[((size_t)bh * 2048 + s + i) * 64 + hd] = f2bf(acc[mt][nt][i] * qs);
            }
        }
    }
}

// ---------------------------------------------------------------------------
// Flash attention (causal) v10: QBLK=128 (32 rows/wave as 2x16 sub-tiles).
// Halves total tile-iterations (16896 -> 8704): half the barriers, half the
// K/V staging, half the K/V global reads. P LDS is reused serially for the
// two row-sets (wave-private, lgkm-ordered). K/V double-buffered, ONE
// barrier per tile (r9 pattern). LDS 41.2 KB -> 3 blocks/CU.
// Load balance: CU's (heavy,light) pair sums to 36 tiles for every pairing.
// ---------------------------------------------------------------------------
#define SOFTPV(qfa, qfb, myq, m_s, l_s, o) do { \
    floatx4 s[4]; \
    _Pragma("unroll") \
    for (int nt = 0; nt < 4; nt++) { \
        const short8 kf0 = KV8(Kc, nt * 16 + lrow, lquad * 16); \
        const short8 kf1 = KV8(Kc, nt * 16 + lrow, 64 + lquad * 16); \
        floatx4 a = (floatx4){0.f, 0.f, 0.f, 0.f}; \
        a = MFMA(kf0, (qfa), a); \
        a = MFMA(kf1, (qfb), a); \
        s[nt] = a; \
    } \
    if (kt >= ntiles - 2) {   /* diagonal region, wave-uniform gate */ \
        _Pragma("unroll") \
        for (int nt = 0; nt < 4; nt++) \
            _Pragma("unroll") \
            for (int i = 0; i < 4; i++) \
                if (kt * 64 + nt * 16 + lquad * 4 + i > (myq)) s[nt][i] = NEGINF; \
    } \
    float mx = NEGINF; \
    _Pragma("unroll") \
    for (int nt = 0; nt < 4; nt++) \
        mx = fmaxf(mx, fmaxf(fmaxf(s[nt][0], s[nt][1]), fmaxf(s[nt][2], s[nt][3]))); \
    mx = fmaxf(mx, __shfl_xor(mx, 16)); \
    mx = fmaxf(mx, __shfl_xor(mx, 32)); \
    if (!__all(mx <= (m_s) + 8.0f)) {   /* defer-max (T13) */ \
        const float mnew = fmaxf((m_s), mx); \
        const float alpha = fexp2((m_s) - mnew); \
        (m_s) = mnew; \
        (l_s) *= alpha; \
        _Pragma("unroll") \
        for (int ht = 0; ht < 4; ht++) \
            _Pragma("unroll") \
            for (int i = 0; i < 4; i++) (o)[ht][i] *= alpha; \
    } \
    float sum = 0.f; \
    _Pragma("unroll") \
    for (int nt = 0; nt < 4; nt++) \
        _Pragma("unroll") \
        for (int i = 0; i < 4; i++) { \
            const float pv = fexp2(s[nt][i] - (m_s)); \
            s[nt][i] = pv; \
            sum += pv; \
        } \
    sum += __shfl_xor(sum, 16); \
    sum += __shfl_xor(sum, 32); \
    (l_s) += sum; \
    _Pragma("unroll") \
    for (int nt = 0; nt < 4; nt++) { \
        uint2 pk; \
        pk.x = cvtpk_bf16(s[nt][0], s[nt][1]); \
        pk.y = cvtpk_bf16(s[nt][2], s[nt][3]); \
        *(uint2*)&P[wave][lrow][nt * 16 + lquad * 4] = pk; \
    } \
    _Pragma("unroll") \
    for (int st = 0; st < 2; st++) { \
        const short8 pf = *(const short8*)&P[wave][lrow][st * 32 + lquad * 8]; \
        _Pragma("unroll") \
        for (int ht = 0; ht < 4; ht++) { \
            const short8 vf = KV8(Vc, ht * 16 + lrow, st * 64 + lquad * 16); \
            (o)[ht] = MFMA(vf, pf, (o)[ht]); \
        } \
    } \
} while (0)

__global__ __launch_bounds__(256, 3) void attn_kernel(
    const u16* __restrict__ Q, const u16* __restrict__ Kk,
    const u16* __restrict__ VT, u16* __restrict__ ctx)
{
    __shared__ __align__(16) u16 Ks[2][64 * 64];
    __shared__ __align__(16) u16 Vs[2][64 * 64];
    __shared__ __align__(16) u16 P[4][16][72];
    const int tid = threadIdx.x, wave = tid >> 6, lane = tid & 63;
    const int lrow = lane & 15, lquad = lane >> 4;
    const float NEGINF = -__builtin_inff();

    const int bh = blockIdx.x & 31;
    const int g = blockIdx.x >> 5;            // 0..15
    const int qb = (g < 8) ? (15 - g) : (g - 8);
    const int ntiles = 2 * qb + 2;
    const int q0 = qb * 128 + wave * 32;

    const u16* Qb = Q  + (size_t)bh * 2048 * 64;
    const u16* Kb = Kk + (size_t)bh * 2048 * 64;
    const u16* Vb = VT + (size_t)bh * 64 * 2048;

    const short8 qf00 = *(const short8*)&Qb[(size_t)(q0 + lrow) * 64 + lquad * 8];
    const short8 qf01 = *(const short8*)&Qb[(size_t)(q0 + lrow) * 64 + 32 + lquad * 8];
    const short8 qf10 = *(const short8*)&Qb[(size_t)(q0 + 16 + lrow) * 64 + lquad * 8];
    const short8 qf11 = *(const short8*)&Qb[(size_t)(q0 + 16 + lrow) * 64 + 32 + lquad * 8];

    const int myq0 = q0 + lrow, myq1 = q0 + 16 + lrow;
    float m0 = NEGINF, l0 = 0.f, m1 = NEGINF, l1 = 0.f;
    floatx4 o0[4], o1[4];
#pragma unroll
    for (int i = 0; i < 4; i++) {
        o0[i] = (floatx4){0.f, 0.f, 0.f, 0.f};
        o1[i] = (floatx4){0.f, 0.f, 0.f, 0.f};
    }

    const int r0 = tid >> 3, r1 = r0 + 32;    // staging rows (0..63 across block)
    const int ce = (tid & 7) * 8;             // element col (global)
    const int cb = (tid & 7) * 16;            // byte col (LDS, pre-swizzle)

    short8 kreg0 = *(const short8*)&Kb[(size_t)r0 * 64 + ce];
    short8 kreg1 = *(const short8*)&Kb[(size_t)r1 * 64 + ce];
    short8 vreg0 = *(const short8*)&Vb[(size_t)r0 * 2048 + ce];
    short8 vreg1 = *(const short8*)&Vb[(size_t)r1 * 2048 + ce];

    for (int kt = 0; kt < ntiles; kt++) {
        u16* Kc = Ks[kt & 1];
        u16* Vc = Vs[kt & 1];
        KV8(Kc, r0, cb) = kreg0;
        KV8(Kc, r1, cb) = kreg1;
        KV8(Vc, r0, cb) = vreg0;
        KV8(Vc, r1, cb) = vreg1;
        if (kt + 1 < ntiles) {
            kreg0 = *(const short8*)&Kb[(size_t)((kt + 1) * 64 + r0) * 64 + ce];
            kreg1 = *(const short8*)&Kb[(size_t)((kt + 1) * 64 + r1) * 64 + ce];
            vreg0 = *(const short8*)&Vb[(size_t)r0 * 2048 + (kt + 1) * 64 + ce];
            vreg1 = *(const short8*)&Vb[(size_t)r1 * 2048 + (kt + 1) * 64 + ce];
        }
        __syncthreads();              // ONE barrier per tile

        SOFTPV(qf00, qf01, myq0, m0, l0, o0);   // row-set 0 (rows q0..q0+15)
        SOFTPV(qf10, qf11, myq1, m1, l1, o1);   // row-set 1 (rows q0+16..q0+31)
    }

    const int b_ = bh >> 4, h_ = bh & 15;
    const float inv0 = 1.0f / l0;
    const float inv1 = 1.0f / l1;
#pragma unroll
    for (int ht = 0; ht < 4; ht++) {
        uint2 pk;
        pk.x = cvtpk_bf16(o0[ht][0] * inv0, o0[ht][1] * inv0);
        pk.y = cvtpk_bf16(o0[ht][2] * inv0, o0[ht][3] * inv0);
        *(uint2*)&ctx[((size_t)(b_ * 2048 + q0 + lrow)) * 1024 + h_ * 64 + ht * 16 + lquad * 4] = pk;
        pk.x = cvtpk_bf16(o1[ht][0] * inv1, o1[ht][1] * inv1);
        pk.y = cvtpk_bf16(o1[ht][2] * inv1, o1[ht][3] * inv1);
        *(uint2*)&ctx[((size_t)(b_ * 2048 + q0 + 16 + lrow)) * 1024 + h_ * 64 + ht * 16 + lquad * 4] = pk;
    }
}

// ---------------------------------------------------------------------------
// Output projection: same BK=64 structure; epilogue adds bias, stores fp32.
// ---------------------------------------------------------------------------
__global__ __launch_bounds__(256) void gemm_out_kernel(
    const u16* __restrict__ X, const u16* __restrict__ WT,
    const float* __restrict__ bias, float* __restrict__ out)
{
    __shared__ __align__(16) u16 As[128 * 64];
    __shared__ __align__(16) u16 Bs[128 * 64];
    const int bid = blockIdx.x;
    const int xcd = bid & 7;
    const int idx = bid >> 3;          // 0..31
    const int rr  = idx >> 3;          // 0..3
    const int nn  = idx & 7;           // 0..7
    const int m0 = (xcd * 4 + rr) * 128;
    const int n0 = nn * 128;
    const int tid = threadIdx.x;
    const int wave = tid >> 6, lane = tid & 63;
    const int lrow = lane & 15, lquad = lane >> 4;
    const int wr = (wave >> 1) * 64, wc = (wave & 1) * 64;

    const int stg_r = tid >> 3;
    const int stg_c = ((tid & 7) ^ ((tid >> 3) & 7)) * 8;
    const u16* gA = &X[(size_t)(m0 + stg_r) * 1024 + stg_c];
    const u16* gB = &WT[(size_t)(n0 + stg_r) * 1024 + stg_c];

    floatx4 acc[4][4];
#pragma unroll
    for (int mt = 0; mt < 4; mt++)
#pragma unroll
        for (int nt = 0; nt < 4; nt++) acc[mt][nt] = (floatx4){0.f, 0.f, 0.f, 0.f};

    GEMM_K_LOOP64();

#pragma unroll
    for (int mt = 0; mt < 4; mt++) {
        const int gm = m0 + wr + mt * 16 + lquad * 4;
#pragma unroll
        for (int nt = 0; nt < 4; nt++) {
            const int gn = n0 + wc + nt * 16 + lrow;
            const float bv = bias[gn];
#pragma unroll
            for (int i = 0; i < 4; i++)
                out[(size_t)(gm + i) * 1024 + gn] = acc[mt][nt][i] + bv;
        }
    }
}

// ---------------------------------------------------------------------------
extern "C" void kernel_launch(void* const* d_in, const int* in_sizes, int n_in,
                              void* d_out, int out_size, void* d_ws, size_t ws_size,
                              hipStream_t stream) {
    u16* ws = (u16*)d_ws + 64;

    const size_t MB1 = 1024 * 1024;
    u16* WT   = ws;              // 4 transposed weights (bf16)
    u16* Qw   = ws + 4 * MB1;    // [bh][2048][64], pre-scaled by 0.125*log2e
    u16* Kw   = ws + 8 * MB1;    // [bh][2048][64]
    u16* VTw  = ws + 12 * MB1;   // [bh][64][2048]
    u16* ctxw = ws + 16 * MB1;   // [4096][1024]
    u16* Xbf  = ws + 20 * MB1;   // x as bf16 [4096][1024]

    prep_kernel<<<dim3(32, 32, 5), dim3(32, 8), 0, stream>>>(
        (const float*)d_in[0], (const float*)d_in[1], (const float*)d_in[2],
        (const float*)d_in[3], (const float*)d_in[4], WT, Xbf);
    gemm_qkv_kernel<<<768, 256, 0, stream>>>(Xbf, WT, Qw, Kw, VTw);
    attn_kernel<<<512, 256, 0, stream>>>(Qw, Kw, VTw, ctxw);
    gemm_out_kernel<<<256, 256, 0, stream>>>(ctxw, WT + 3 * MB1, (const float*)d_in[5], (float*)d_out);
}

// Round 11
// 178.818 us; speedup vs baseline: 1.0588x; 1.0588x over previous
//
#include <hip/hip_runtime.h>
#include <stdint.h>

typedef unsigned short u16;
typedef __attribute__((ext_vector_type(8))) short short8;
typedef __attribute__((ext_vector_type(4))) float floatx4;
typedef __attribute__((ext_vector_type(4))) u16 ushort4v;

typedef __attribute__((address_space(1))) const uint32_t gu32;
typedef __attribute__((address_space(3))) uint32_t lu32;

#define MFMA(a, b, c) __builtin_amdgcn_mfma_f32_16x16x32_bf16((a), (b), (c), 0, 0, 0)

__device__ __forceinline__ u16 f2bf(float f) {
    union { float f; uint32_t u; } x; x.f = f;
    uint32_t u = x.u;
    u += 0x7fffu + ((u >> 16) & 1u);
    return (u16)(u >> 16);
}

// packed f32x2 -> bf16x2 (RNE), single instruction (T12 primitive)
__device__ __forceinline__ uint32_t cvtpk_bf16(float lo, float hi) {
    uint32_t r;
    asm("v_cvt_pk_bf16_f32 %0, %1, %2" : "=v"(r) : "v"(lo), "v"(hi));
    return r;
}

// hardware exp2 (v_exp_f32 IS exp2)
__device__ __forceinline__ float fexp2(float x) {
#if defined(__has_builtin)
#if __has_builtin(__builtin_amdgcn_exp2f)
    return __builtin_amdgcn_exp2f(x);
#else
    return exp2f(x);
#endif
#else
    return exp2f(x);
#endif
}

// async global->LDS DMA, 16B per lane; lds base must be wave-uniform,
// HW scatters to base + lane*16 (m104/m108).
__device__ __forceinline__ void async16(u16* lds, const u16* g) {
    __builtin_amdgcn_global_load_lds((gu32*)g, (lu32*)lds, 16, 0, 0);
}

// K/V LDS tiles (attn): [64 rows][128 B], XOR-swizzled: byte ^= (row&7)<<4.
#define KV8(buf, row, byteInRow) \
    (*(short8*)((char*)(buf) + (((row) << 7) + ((byteInRow) ^ (((row) & 7) << 4)))))

// 0.125 (1/sqrt(64)) * log2(e): folded into Q so softmax runs in exp2 domain.
#define Q_SCALE_LOG2E 0.18033688011112042f

// ---------------------------------------------------------------------------
// prep: z=0..3 transpose W_z [k][n] fp32 -> WT [n][k] bf16; z=4 convert x.
// ---------------------------------------------------------------------------
__global__ __launch_bounds__(256) void prep_kernel(
    const float* __restrict__ x,
    const float* __restrict__ W0, const float* __restrict__ W1,
    const float* __restrict__ W2, const float* __restrict__ W3,
    u16* __restrict__ WT, u16* __restrict__ Xbf)
{
    const int z = blockIdx.z;
    const int tx = threadIdx.x, ty = threadIdx.y;
    if (z == 4) {
        const int bid = blockIdx.y * 32 + blockIdx.x;
        const int t = ty * 32 + tx;
        const size_t base = ((size_t)bid * 256 + t) * 16;
        const float* xf = x + base;
        short8 v0, v1;
#pragma unroll
        for (int j = 0; j < 8; j++) v0[j] = (short)f2bf(xf[j]);
#pragma unroll
        for (int j = 0; j < 8; j++) v1[j] = (short)f2bf(xf[8 + j]);
        *(short8*)&Xbf[base] = v0;
        *(short8*)&Xbf[base + 8] = v1;
        return;
    }
    __shared__ u16 tile[32][33];
    const float* W = (z == 0) ? W0 : (z == 1) ? W1 : (z == 2) ? W2 : W3;
    u16* dst = WT + (size_t)z * 1024 * 1024;
    const int n0 = blockIdx.x * 32, k0 = blockIdx.y * 32;
#pragma unroll
    for (int i = 0; i < 4; i++)
        tile[ty + i * 8][tx] = f2bf(W[(size_t)(k0 + ty + i * 8) * 1024 + n0 + tx]);
    __syncthreads();
#pragma unroll
    for (int i = 0; i < 4; i++)
        dst[(size_t)(n0 + ty + i * 8) * 1024 + k0 + tx] = tile[tx][ty + i * 8];
}

// ---------------------------------------------------------------------------
// GEMM core (round-6, verified 44.3 us): BK=64 / 128x128 tile / 4 waves /
// single 32-KB LDS buffer, swizzled (inverse-swizzled source + XOR'd read).
// ---------------------------------------------------------------------------
#define GSTAGE64(buf, gptr, kk) do { \
    _Pragma("unroll") \
    for (int i_ = 0; i_ < 4; i_++) \
        async16((buf) + wave * 512 + i_ * 2048, (gptr) + (kk) + (size_t)i_ * 32 * 1024); \
} while (0)

// frag read: row = base + fr*16 + lrow (row&7 == lrow&7); granule g = ks*4+lquad
#define GFRAG64(buf, base, ks, fr) \
    (*(const short8*)&(buf)[((base) + (fr) * 16 + lrow) * 64 + ((((ks) * 4 + lquad) ^ (lrow & 7)) * 8)])

#define GCOMPUTE64() do { \
    _Pragma("unroll") \
    for (int ks = 0; ks < 2; ks++) { \
        short8 af[4], bfv[4]; \
        _Pragma("unroll") \
        for (int mt = 0; mt < 4; mt++) af[mt] = GFRAG64(As, wr, ks, mt); \
        _Pragma("unroll") \
        for (int nt = 0; nt < 4; nt++) bfv[nt] = GFRAG64(Bs, wc, ks, nt); \
        _Pragma("unroll") \
        for (int mt = 0; mt < 4; mt++) \
            _Pragma("unroll") \
            for (int nt = 0; nt < 4; nt++) \
                acc[mt][nt] = MFMA(af[mt], bfv[nt], acc[mt][nt]); \
    } \
} while (0)

#define GEMM_K_LOOP64() do { \
    for (int kk = 0; kk < 1024; kk += 64) { \
        __syncthreads(); \
        GSTAGE64(As, gA, kk); \
        GSTAGE64(Bs, gB, kk); \
        __syncthreads(); \
        GCOMPUTE64(); \
    } \
} while (0)

// ---------------------------------------------------------------------------
// QKV GEMM: 768 blocks (xcd-striped), BK=64 structure above.
// Q outputs pre-scaled by 0.125*log2e (softmax runs in exp2 domain).
// ---------------------------------------------------------------------------
__global__ __launch_bounds__(256) void gemm_qkv_kernel(
    const u16* __restrict__ X, const u16* __restrict__ WT,
    u16* __restrict__ Q, u16* __restrict__ Kout, u16* __restrict__ VT)
{
    __shared__ __align__(16) u16 As[128 * 64];
    __shared__ __align__(16) u16 Bs[128 * 64];
    const int bid = blockIdx.x;
    const int xcd = bid & 7;
    const int idx = bid >> 3;          // 0..95
    const int mat = idx >> 5;          // 0..2
    const int rr  = (idx >> 3) & 3;    // 0..3
    const int nn  = idx & 7;           // 0..7
    const int m0 = (xcd * 4 + rr) * 128;
    const int n0 = nn * 128;
    const u16* BW = WT + (size_t)mat * 1024 * 1024;
    const int tid = threadIdx.x;
    const int wave = tid >> 6, lane = tid & 63;
    const int lrow = lane & 15, lquad = lane >> 4;
    const int wr = (wave >> 1) * 64, wc = (wave & 1) * 64;

    const int stg_r = tid >> 3;                                  // 0..31
    const int stg_c = ((tid & 7) ^ ((tid >> 3) & 7)) * 8;        // inv-swizzled col
    const u16* gA = &X[(size_t)(m0 + stg_r) * 1024 + stg_c];
    const u16* gB = &BW[(size_t)(n0 + stg_r) * 1024 + stg_c];

    floatx4 acc[4][4];
#pragma unroll
    for (int mt = 0; mt < 4; mt++)
#pragma unroll
        for (int nt = 0; nt < 4; nt++) acc[mt][nt] = (floatx4){0.f, 0.f, 0.f, 0.f};

    GEMM_K_LOOP64();

    const float qs = (mat == 0) ? Q_SCALE_LOG2E : 1.0f;
#pragma unroll
    for (int mt = 0; mt < 4; mt++) {
        const int gm = m0 + wr + mt * 16 + lquad * 4;
        const int b_ = gm >> 11;
        const int s  = gm & 2047;
#pragma unroll
        for (int nt = 0; nt < 4; nt++) {
            const int gn = n0 + wc + nt * 16 + lrow;
            const int h = gn >> 6, hd = gn & 63;
            const int bh = b_ * 16 + h;
            if (mat == 2) {
                ushort4v v;
#pragma unroll
                for (int i = 0; i < 4; i++) v[i] = f2bf(acc[mt][nt][i]);
                *(ushort4v*)&VT[((size_t)bh * 64 + hd) * 2048 + s] = v;
            } else {
                u16* dst = (mat == 0) ? Q : Kout;
#pragma unroll
                for (int i = 0; i < 4; i++)
                    dst[((size_t)bh * 2048 + s + i) * 64 + hd] = f2bf(acc[mt][nt][i] * qs);
            }
        }
    }
}

// ---------------------------------------------------------------------------
// Flash attention (causal), round-9 structure (verified best: K AND V
// double-buffered, ONE barrier per tile, P stride 72, QBLK=64, 1024 blocks)
// + T5: s_setprio(1) around the MFMA clusters (m191: +4-7% on attn with
// multiple independent blocks per CU -- our regime: 3 blocks/CU at
// independent phases).
// ---------------------------------------------------------------------------
__global__ __launch_bounds__(256, 3) void attn_kernel(
    const u16* __restrict__ Q, const u16* __restrict__ Kk,
    const u16* __restrict__ VT, u16* __restrict__ ctx)
{
    __shared__ __align__(16) u16 Ks[2][64 * 64];
    __shared__ __align__(16) u16 Vs[2][64 * 64];
    __shared__ __align__(16) u16 P[4][16][72];
    const int tid = threadIdx.x, wave = tid >> 6, lane = tid & 63;
    const int lrow = lane & 15, lquad = lane >> 4;
    const float NEGINF = -__builtin_inff();

    const int bh = blockIdx.x & 31;
    const int g = blockIdx.x >> 5;
    const int qb = (g < 16) ? (31 - g) : (g - 16);
    const int ntiles = qb + 1;
    const int q0 = qb * 64 + wave * 16;

    const u16* Qb = Q  + (size_t)bh * 2048 * 64;
    const u16* Kb = Kk + (size_t)bh * 2048 * 64;
    const u16* Vb = VT + (size_t)bh * 64 * 2048;

    const short8 qf0 = *(const short8*)&Qb[(size_t)(q0 + lrow) * 64 + lquad * 8];
    const short8 qf1 = *(const short8*)&Qb[(size_t)(q0 + lrow) * 64 + 32 + lquad * 8];

    const int myq = q0 + lrow;
    float m_s = NEGINF, l_s = 0.f;
    floatx4 o[4];
#pragma unroll
    for (int i = 0; i < 4; i++) o[i] = (floatx4){0.f, 0.f, 0.f, 0.f};

    const int r0 = tid >> 3, r1 = r0 + 32;    // staging rows (0..63 across block)
    const int ce = (tid & 7) * 8;             // element col (global)
    const int cb = (tid & 7) * 16;            // byte col (LDS, pre-swizzle)

    short8 kreg0 = *(const short8*)&Kb[(size_t)r0 * 64 + ce];
    short8 kreg1 = *(const short8*)&Kb[(size_t)r1 * 64 + ce];
    short8 vreg0 = *(const short8*)&Vb[(size_t)r0 * 2048 + ce];
    short8 vreg1 = *(const short8*)&Vb[(size_t)r1 * 2048 + ce];

    for (int kt = 0; kt < ntiles; kt++) {
        u16* Kc = Ks[kt & 1];
        u16* Vc = Vs[kt & 1];
        KV8(Kc, r0, cb) = kreg0;
        KV8(Kc, r1, cb) = kreg1;
        KV8(Vc, r0, cb) = vreg0;
        KV8(Vc, r1, cb) = vreg1;
        if (kt + 1 < ntiles) {
            kreg0 = *(const short8*)&Kb[(size_t)((kt + 1) * 64 + r0) * 64 + ce];
            kreg1 = *(const short8*)&Kb[(size_t)((kt + 1) * 64 + r1) * 64 + ce];
            vreg0 = *(const short8*)&Vb[(size_t)r0 * 2048 + (kt + 1) * 64 + ce];
            vreg1 = *(const short8*)&Vb[(size_t)r1 * 2048 + (kt + 1) * 64 + ce];
        }
        __syncthreads();              // ONE barrier per tile

        floatx4 s[4];
#pragma unroll
        for (int nt = 0; nt < 4; nt++) {
            const short8 kf0 = KV8(Kc, nt * 16 + lrow, lquad * 16);
            const short8 kf1 = KV8(Kc, nt * 16 + lrow, 64 + lquad * 16);
            floatx4 a = (floatx4){0.f, 0.f, 0.f, 0.f};
            __builtin_amdgcn_s_setprio(1);
            a = MFMA(kf0, qf0, a);
            a = MFMA(kf1, qf1, a);
            __builtin_amdgcn_s_setprio(0);
            s[nt] = a;
        }

        if (kt == ntiles - 1) {   // causal mask, diag tile only (wave-uniform)
#pragma unroll
            for (int nt = 0; nt < 4; nt++)
#pragma unroll
                for (int i = 0; i < 4; i++)
                    if (kt * 64 + nt * 16 + lquad * 4 + i > myq) s[nt][i] = NEGINF;
        }

        float mx = NEGINF;
#pragma unroll
        for (int nt = 0; nt < 4; nt++)
            mx = fmaxf(mx, fmaxf(fmaxf(s[nt][0], s[nt][1]),
                                 fmaxf(s[nt][2], s[nt][3])));
        mx = fmaxf(mx, __shfl_xor(mx, 16));
        mx = fmaxf(mx, __shfl_xor(mx, 32));

        // defer-max (T13): only rescale when some row's max grew by >8.
        if (!__all(mx <= m_s + 8.0f)) {
            const float mnew = fmaxf(m_s, mx);
            const float alpha = fexp2(m_s - mnew);
            m_s = mnew;
            l_s *= alpha;
#pragma unroll
            for (int ht = 0; ht < 4; ht++)
#pragma unroll
                for (int i = 0; i < 4; i++) o[ht][i] *= alpha;
        }

        float sum = 0.f;
#pragma unroll
        for (int nt = 0; nt < 4; nt++)
#pragma unroll
            for (int i = 0; i < 4; i++) {
                const float pv = fexp2(s[nt][i] - m_s);
                s[nt][i] = pv;
                sum += pv;
            }
        sum += __shfl_xor(sum, 16);
        sum += __shfl_xor(sum, 32);
        l_s += sum;

#pragma unroll
        for (int nt = 0; nt < 4; nt++) {
            uint2 pk;
            pk.x = cvtpk_bf16(s[nt][0], s[nt][1]);
            pk.y = cvtpk_bf16(s[nt][2], s[nt][3]);
            *(uint2*)&P[wave][lrow][nt * 16 + lquad * 4] = pk;
        }
#pragma unroll
        for (int st = 0; st < 2; st++) {
            const short8 pf = *(const short8*)&P[wave][lrow][st * 32 + lquad * 8];
            __builtin_amdgcn_s_setprio(1);
#pragma unroll
            for (int ht = 0; ht < 4; ht++) {
                const short8 vf = KV8(Vc, ht * 16 + lrow, st * 64 + lquad * 16);
                o[ht] = MFMA(vf, pf, o[ht]);
            }
            __builtin_amdgcn_s_setprio(0);
        }
    }

    const int b_ = bh >> 4, h_ = bh & 15;
    const float inv_l = 1.0f / l_s;
#pragma unroll
    for (int ht = 0; ht < 4; ht++) {
        uint2 pk;
        pk.x = cvtpk_bf16(o[ht][0] * inv_l, o[ht][1] * inv_l);
        pk.y = cvtpk_bf16(o[ht][2] * inv_l, o[ht][3] * inv_l);
        *(uint2*)&ctx[((size_t)(b_ * 2048 + q0 + lrow)) * 1024 + h_ * 64 + ht * 16 + lquad * 4] = pk;
    }
}

// ---------------------------------------------------------------------------
// Output projection: same BK=64 structure; epilogue adds bias, stores fp32.
// ---------------------------------------------------------------------------
__global__ __launch_bounds__(256) void gemm_out_kernel(
    const u16* __restrict__ X, const u16* __restrict__ WT,
    const float* __restrict__ bias, float* __restrict__ out)
{
    __shared__ __align__(16) u16 As[128 * 64];
    __shared__ __align__(16) u16 Bs[128 * 64];
    const int bid = blockIdx.x;
    const int xcd = bid & 7;
    const int idx = bid >> 3;          // 0..31
    const int rr  = idx >> 3;          // 0..3
    const int nn  = idx & 7;           // 0..7
    const int m0 = (xcd * 4 + rr) * 128;
    const int n0 = nn * 128;
    const int tid = threadIdx.x;
    const int wave = tid >> 6, lane = tid & 63;
    const int lrow = lane & 15, lquad = lane >> 4;
    const int wr = (wave >> 1) * 64, wc = (wave & 1) * 64;

    const int stg_r = tid >> 3;
    const int stg_c = ((tid & 7) ^ ((tid >> 3) & 7)) * 8;
    const u16* gA = &X[(size_t)(m0 + stg_r) * 1024 + stg_c];
    const u16* gB = &WT[(size_t)(n0 + stg_r) * 1024 + stg_c];

    floatx4 acc[4][4];
#pragma unroll
    for (int mt = 0; mt < 4; mt++)
#pragma unroll
        for (int nt = 0; nt < 4; nt++) acc[mt][nt] = (floatx4){0.f, 0.f, 0.f, 0.f};

    GEMM_K_LOOP64();

#pragma unroll
    for (int mt = 0; mt < 4; mt++) {
        const int gm = m0 + wr + mt * 16 + lquad * 4;
#pragma unroll
        for (int nt = 0; nt < 4; nt++) {
            const int gn = n0 + wc + nt * 16 + lrow;
            const float bv = bias[gn];
#pragma unroll
            for (int i = 0; i < 4; i++)
                out[(size_t)(gm + i) * 1024 + gn] = acc[mt][nt][i] + bv;
        }
    }
}

// ---------------------------------------------------------------------------
extern "C" void kernel_launch(void* const* d_in, const int* in_sizes, int n_in,
                              void* d_out, int out_size, void* d_ws, size_t ws_size,
                              hipStream_t stream) {
    u16* ws = (u16*)d_ws + 64;

    const size_t MB1 = 1024 * 1024;
    u16* WT   = ws;              // 4 transposed weights (bf16)
    u16* Qw   = ws + 4 * MB1;    // [bh][2048][64], pre-scaled by 0.125*log2e
    u16* Kw   = ws + 8 * MB1;    // [bh][2048][64]
    u16* VTw  = ws + 12 * MB1;   // [bh][64][2048]
    u16* ctxw = ws + 16 * MB1;   // [4096][1024]
    u16* Xbf  = ws + 20 * MB1;   // x as bf16 [4096][1024]

    prep_kernel<<<dim3(32, 32, 5), dim3(32, 8), 0, stream>>>(
        (const float*)d_in[0], (const float*)d_in[1], (const float*)d_in[2],
        (const float*)d_in[3], (const float*)d_in[4], WT, Xbf);
    gemm_qkv_kernel<<<768, 256, 0, stream>>>(Xbf, WT, Qw, Kw, VTw);
    attn_kernel<<<1024, 256, 0, stream>>>(Qw, Kw, VTw, ctxw);
    gemm_out_kernel<<<256, 256, 0, stream>>>(ctxw, WT + 3 * MB1, (const float*)d_in[5], (float*)d_out);
}

// Round 12
// 172.413 us; speedup vs baseline: 1.0982x; 1.0371x over previous
//
#include <hip/hip_runtime.h>
#include <stdint.h>

typedef unsigned short u16;
typedef __attribute__((ext_vector_type(8))) short short8;
typedef __attribute__((ext_vector_type(4))) float floatx4;
typedef __attribute__((ext_vector_type(4))) u16 ushort4v;

typedef __attribute__((address_space(1))) const uint32_t gu32;
typedef __attribute__((address_space(3))) uint32_t lu32;

#define MFMA(a, b, c) __builtin_amdgcn_mfma_f32_16x16x32_bf16((a), (b), (c), 0, 0, 0)

__device__ __forceinline__ u16 f2bf(float f) {
    union { float f; uint32_t u; } x; x.f = f;
    uint32_t u = x.u;
    u += 0x7fffu + ((u >> 16) & 1u);
    return (u16)(u >> 16);
}

// packed f32x2 -> bf16x2 (RNE), single instruction (T12 primitive)
__device__ __forceinline__ uint32_t cvtpk_bf16(float lo, float hi) {
    uint32_t r;
    asm("v_cvt_pk_bf16_f32 %0, %1, %2" : "=v"(r) : "v"(lo), "v"(hi));
    return r;
}

// hardware exp2 (v_exp_f32 IS exp2)
__device__ __forceinline__ float fexp2(float x) {
#if defined(__has_builtin)
#if __has_builtin(__builtin_amdgcn_exp2f)
    return __builtin_amdgcn_exp2f(x);
#else
    return exp2f(x);
#endif
#else
    return exp2f(x);
#endif
}

// async global->LDS DMA, 16B per lane; lds base must be wave-uniform,
// HW scatters to base + lane*16 (m104/m108).
__device__ __forceinline__ void async16(u16* lds, const u16* g) {
    __builtin_amdgcn_global_load_lds((gu32*)g, (lu32*)lds, 16, 0, 0);
}

// K/V LDS tiles (attn): [64 rows][128 B], XOR-swizzled: byte ^= (row&7)<<4.
#define KV8(buf, row, byteInRow) \
    (*(short8*)((char*)(buf) + (((row) << 7) + ((byteInRow) ^ (((row) & 7) << 4)))))

// 0.125 (1/sqrt(64)) * log2(e): folded into Q so softmax runs in exp2 domain.
#define Q_SCALE_LOG2E 0.18033688011112042f

// ---------------------------------------------------------------------------
// prep: z=0..3 transpose W_z [k][n] fp32 -> WT [n][k] bf16; z=4 convert x.
// ---------------------------------------------------------------------------
__global__ __launch_bounds__(256) void prep_kernel(
    const float* __restrict__ x,
    const float* __restrict__ W0, const float* __restrict__ W1,
    const float* __restrict__ W2, const float* __restrict__ W3,
    u16* __restrict__ WT, u16* __restrict__ Xbf)
{
    const int z = blockIdx.z;
    const int tx = threadIdx.x, ty = threadIdx.y;
    if (z == 4) {
        const int bid = blockIdx.y * 32 + blockIdx.x;
        const int t = ty * 32 + tx;
        const size_t base = ((size_t)bid * 256 + t) * 16;
        const float* xf = x + base;
        short8 v0, v1;
#pragma unroll
        for (int j = 0; j < 8; j++) v0[j] = (short)f2bf(xf[j]);
#pragma unroll
        for (int j = 0; j < 8; j++) v1[j] = (short)f2bf(xf[8 + j]);
        *(short8*)&Xbf[base] = v0;
        *(short8*)&Xbf[base + 8] = v1;
        return;
    }
    __shared__ u16 tile[32][33];
    const float* W = (z == 0) ? W0 : (z == 1) ? W1 : (z == 2) ? W2 : W3;
    u16* dst = WT + (size_t)z * 1024 * 1024;
    const int n0 = blockIdx.x * 32, k0 = blockIdx.y * 32;
#pragma unroll
    for (int i = 0; i < 4; i++)
        tile[ty + i * 8][tx] = f2bf(W[(size_t)(k0 + ty + i * 8) * 1024 + n0 + tx]);
    __syncthreads();
#pragma unroll
    for (int i = 0; i < 4; i++)
        dst[(size_t)(n0 + ty + i * 8) * 1024 + k0 + tx] = tile[tx][ty + i * 8];
}

// ---------------------------------------------------------------------------
// GEMM core v12: 128m x 64n tile / BK=64 / 4 waves (2m x 2n, wave tile
// 64x32) / single LDS buffer A[128][64]+B[64][64] = 24 KB -> 6 blocks/CU.
// r10 lesson inverted: blocks/CU is the scarce resource in this
// latency-bound regime, so shrink the tile to double TLP (qkv 3 -> 6
// blocks/CU). Extra A-panel re-reads are per-XCD L2 hits (1 MB/XCD).
// Swizzle identical to r6/r8 (inverse-swizzled source + XOR'd ds_read;
// B rows 64: row&7 == (tid>>3)&7 still holds).
// ---------------------------------------------------------------------------
#define GSTAGE_A(buf, gptr, kk) do { \
    _Pragma("unroll") \
    for (int i_ = 0; i_ < 4; i_++) \
        async16((buf) + wave * 512 + i_ * 2048, (gptr) + (kk) + (size_t)i_ * 32 * 1024); \
} while (0)

#define GSTAGE_B2(buf, gptr, kk) do { \
    _Pragma("unroll") \
    for (int i_ = 0; i_ < 2; i_++) \
        async16((buf) + wave * 512 + i_ * 2048, (gptr) + (kk) + (size_t)i_ * 32 * 1024); \
} while (0)

// frag read: row = base + fr*16 + lrow (row&7 == lrow&7); granule g = ks*4+lquad
#define GFRAG64(buf, base, ks, fr) \
    (*(const short8*)&(buf)[((base) + (fr) * 16 + lrow) * 64 + ((((ks) * 4 + lquad) ^ (lrow & 7)) * 8)])

#define GCOMPUTE_N64() do { \
    _Pragma("unroll") \
    for (int ks = 0; ks < 2; ks++) { \
        short8 af[4], bfv[2]; \
        _Pragma("unroll") \
        for (int mt = 0; mt < 4; mt++) af[mt] = GFRAG64(As, wr, ks, mt); \
        _Pragma("unroll") \
        for (int nt = 0; nt < 2; nt++) bfv[nt] = GFRAG64(Bs, wc, ks, nt); \
        _Pragma("unroll") \
        for (int mt = 0; mt < 4; mt++) \
            _Pragma("unroll") \
            for (int nt = 0; nt < 2; nt++) \
                acc[mt][nt] = MFMA(af[mt], bfv[nt], acc[mt][nt]); \
    } \
} while (0)

#define GEMM_K_LOOP_N64() do { \
    for (int kk = 0; kk < 1024; kk += 64) { \
        __syncthreads(); \
        GSTAGE_A(As, gA, kk); \
        GSTAGE_B2(Bs, gB, kk); \
        __syncthreads(); \
        GCOMPUTE_N64(); \
    } \
} while (0)

// ---------------------------------------------------------------------------
// QKV GEMM: 1536 blocks (xcd-striped, 6/CU), 128x64 tiles.
// Q outputs pre-scaled by 0.125*log2e (softmax runs in exp2 domain).
// ---------------------------------------------------------------------------
__global__ __launch_bounds__(256) void gemm_qkv_kernel(
    const u16* __restrict__ X, const u16* __restrict__ WT,
    u16* __restrict__ Q, u16* __restrict__ Kout, u16* __restrict__ VT)
{
    __shared__ __align__(16) u16 As[128 * 64];
    __shared__ __align__(16) u16 Bs[64 * 64];
    const int bid = blockIdx.x;
    const int xcd = bid & 7;
    const int idx = bid >> 3;          // 0..191
    const int mat = idx >> 6;          // 0..2
    const int rem = idx & 63;
    const int rr  = rem >> 4;          // 0..3 -> m-tile within XCD stripe
    const int nn  = rem & 15;          // 0..15 -> 64-col n-tile within mat
    const int m0 = (xcd * 4 + rr) * 128;
    const int n0 = nn * 64;
    const u16* BW = WT + (size_t)mat * 1024 * 1024;
    const int tid = threadIdx.x;
    const int wave = tid >> 6, lane = tid & 63;
    const int lrow = lane & 15, lquad = lane >> 4;
    const int wr = (wave >> 1) * 64;   // 0 / 64
    const int wc = (wave & 1) * 32;    // 0 / 32

    const int stg_r = tid >> 3;                                  // 0..31
    const int stg_c = ((tid & 7) ^ ((tid >> 3) & 7)) * 8;        // inv-swizzled col
    const u16* gA = &X[(size_t)(m0 + stg_r) * 1024 + stg_c];
    const u16* gB = &BW[(size_t)(n0 + stg_r) * 1024 + stg_c];

    floatx4 acc[4][2];
#pragma unroll
    for (int mt = 0; mt < 4; mt++)
#pragma unroll
        for (int nt = 0; nt < 2; nt++) acc[mt][nt] = (floatx4){0.f, 0.f, 0.f, 0.f};

    GEMM_K_LOOP_N64();

    const float qs = (mat == 0) ? Q_SCALE_LOG2E : 1.0f;
#pragma unroll
    for (int mt = 0; mt < 4; mt++) {
        const int gm = m0 + wr + mt * 16 + lquad * 4;
        const int b_ = gm >> 11;
        const int s  = gm & 2047;
#pragma unroll
        for (int nt = 0; nt < 2; nt++) {
            const int gn = n0 + wc + nt * 16 + lrow;
            const int h = gn >> 6, hd = gn & 63;
            const int bh = b_ * 16 + h;
            if (mat == 2) {
                ushort4v v;
#pragma unroll
                for (int i = 0; i < 4; i++) v[i] = f2bf(acc[mt][nt][i]);
                *(ushort4v*)&VT[((size_t)bh * 64 + hd) * 2048 + s] = v;
            } else {
                u16* dst = (mat == 0) ? Q : Kout;
#pragma unroll
                for (int i = 0; i < 4; i++)
                    dst[((size_t)bh * 2048 + s + i) * 64 + hd] = f2bf(acc[mt][nt][i] * qs);
            }
        }
    }
}

// ---------------------------------------------------------------------------
// Flash attention (causal), round-9 structure exactly (verified best):
// K AND V double-buffered, ONE barrier per tile, P stride 72, QBLK=64.
// ---------------------------------------------------------------------------
__global__ __launch_bounds__(256, 3) void attn_kernel(
    const u16* __restrict__ Q, const u16* __restrict__ Kk,
    const u16* __restrict__ VT, u16* __restrict__ ctx)
{
    __shared__ __align__(16) u16 Ks[2][64 * 64];
    __shared__ __align__(16) u16 Vs[2][64 * 64];
    __shared__ __align__(16) u16 P[4][16][72];
    const int tid = threadIdx.x, wave = tid >> 6, lane = tid & 63;
    const int lrow = lane & 15, lquad = lane >> 4;
    const float NEGINF = -__builtin_inff();

    const int bh = blockIdx.x & 31;
    const int g = blockIdx.x >> 5;
    const int qb = (g < 16) ? (31 - g) : (g - 16);
    const int ntiles = qb + 1;
    const int q0 = qb * 64 + wave * 16;

    const u16* Qb = Q  + (size_t)bh * 2048 * 64;
    const u16* Kb = Kk + (size_t)bh * 2048 * 64;
    const u16* Vb = VT + (size_t)bh * 64 * 2048;

    const short8 qf0 = *(const short8*)&Qb[(size_t)(q0 + lrow) * 64 + lquad * 8];
    const short8 qf1 = *(const short8*)&Qb[(size_t)(q0 + lrow) * 64 + 32 + lquad * 8];

    const int myq = q0 + lrow;
    float m_s = NEGINF, l_s = 0.f;
    floatx4 o[4];
#pragma unroll
    for (int i = 0; i < 4; i++) o[i] = (floatx4){0.f, 0.f, 0.f, 0.f};

    const int r0 = tid >> 3, r1 = r0 + 32;    // staging rows (0..63 across block)
    const int ce = (tid & 7) * 8;             // element col (global)
    const int cb = (tid & 7) * 16;            // byte col (LDS, pre-swizzle)

    short8 kreg0 = *(const short8*)&Kb[(size_t)r0 * 64 + ce];
    short8 kreg1 = *(const short8*)&Kb[(size_t)r1 * 64 + ce];
    short8 vreg0 = *(const short8*)&Vb[(size_t)r0 * 2048 + ce];
    short8 vreg1 = *(const short8*)&Vb[(size_t)r1 * 2048 + ce];

    for (int kt = 0; kt < ntiles; kt++) {
        u16* Kc = Ks[kt & 1];
        u16* Vc = Vs[kt & 1];
        KV8(Kc, r0, cb) = kreg0;
        KV8(Kc, r1, cb) = kreg1;
        KV8(Vc, r0, cb) = vreg0;
        KV8(Vc, r1, cb) = vreg1;
        if (kt + 1 < ntiles) {
            kreg0 = *(const short8*)&Kb[(size_t)((kt + 1) * 64 + r0) * 64 + ce];
            kreg1 = *(const short8*)&Kb[(size_t)((kt + 1) * 64 + r1) * 64 + ce];
            vreg0 = *(const short8*)&Vb[(size_t)r0 * 2048 + (kt + 1) * 64 + ce];
            vreg1 = *(const short8*)&Vb[(size_t)r1 * 2048 + (kt + 1) * 64 + ce];
        }
        __syncthreads();              // ONE barrier per tile

        floatx4 s[4];
#pragma unroll
        for (int nt = 0; nt < 4; nt++) {
            const short8 kf0 = KV8(Kc, nt * 16 + lrow, lquad * 16);
            const short8 kf1 = KV8(Kc, nt * 16 + lrow, 64 + lquad * 16);
            floatx4 a = (floatx4){0.f, 0.f, 0.f, 0.f};
            a = MFMA(kf0, qf0, a);
            a = MFMA(kf1, qf1, a);
            s[nt] = a;
        }

        if (kt == ntiles - 1) {   // causal mask, diag tile only (wave-uniform)
#pragma unroll
            for (int nt = 0; nt < 4; nt++)
#pragma unroll
                for (int i = 0; i < 4; i++)
                    if (kt * 64 + nt * 16 + lquad * 4 + i > myq) s[nt][i] = NEGINF;
        }

        float mx = NEGINF;
#pragma unroll
        for (int nt = 0; nt < 4; nt++)
            mx = fmaxf(mx, fmaxf(fmaxf(s[nt][0], s[nt][1]),
                                 fmaxf(s[nt][2], s[nt][3])));
        mx = fmaxf(mx, __shfl_xor(mx, 16));
        mx = fmaxf(mx, __shfl_xor(mx, 32));

        // defer-max (T13): only rescale when some row's max grew by >8.
        if (!__all(mx <= m_s + 8.0f)) {
            const float mnew = fmaxf(m_s, mx);
            const float alpha = fexp2(m_s - mnew);
            m_s = mnew;
            l_s *= alpha;
#pragma unroll
            for (int ht = 0; ht < 4; ht++)
#pragma unroll
                for (int i = 0; i < 4; i++) o[ht][i] *= alpha;
        }

        float sum = 0.f;
#pragma unroll
        for (int nt = 0; nt < 4; nt++)
#pragma unroll
            for (int i = 0; i < 4; i++) {
                const float pv = fexp2(s[nt][i] - m_s);
                s[nt][i] = pv;
                sum += pv;
            }
        sum += __shfl_xor(sum, 16);
        sum += __shfl_xor(sum, 32);
        l_s += sum;

#pragma unroll
        for (int nt = 0; nt < 4; nt++) {
            uint2 pk;
            pk.x = cvtpk_bf16(s[nt][0], s[nt][1]);
            pk.y = cvtpk_bf16(s[nt][2], s[nt][3]);
            *(uint2*)&P[wave][lrow][nt * 16 + lquad * 4] = pk;
        }
#pragma unroll
        for (int st = 0; st < 2; st++) {
            const short8 pf = *(const short8*)&P[wave][lrow][st * 32 + lquad * 8];
#pragma unroll
            for (int ht = 0; ht < 4; ht++) {
                const short8 vf = KV8(Vc, ht * 16 + lrow, st * 64 + lquad * 16);
                o[ht] = MFMA(vf, pf, o[ht]);
            }
        }
    }

    const int b_ = bh >> 4, h_ = bh & 15;
    const float inv_l = 1.0f / l_s;
#pragma unroll
    for (int ht = 0; ht < 4; ht++) {
        uint2 pk;
        pk.x = cvtpk_bf16(o[ht][0] * inv_l, o[ht][1] * inv_l);
        pk.y = cvtpk_bf16(o[ht][2] * inv_l, o[ht][3] * inv_l);
        *(uint2*)&ctx[((size_t)(b_ * 2048 + q0 + lrow)) * 1024 + h_ * 64 + ht * 16 + lquad * 4] = pk;
    }
}

// ---------------------------------------------------------------------------
// Output projection: 512 blocks (2/CU, was 1/CU), 128x64 tiles.
// ---------------------------------------------------------------------------
__global__ __launch_bounds__(256) void gemm_out_kernel(
    const u16* __restrict__ X, const u16* __restrict__ WT,
    const float* __restrict__ bias, float* __restrict__ out)
{
    __shared__ __align__(16) u16 As[128 * 64];
    __shared__ __align__(16) u16 Bs[64 * 64];
    const int bid = blockIdx.x;
    const int xcd = bid & 7;
    const int idx = bid >> 3;          // 0..63
    const int rr  = idx >> 4;          // 0..3
    const int nn  = idx & 15;          // 0..15
    const int m0 = (xcd * 4 + rr) * 128;
    const int n0 = nn * 64;
    const int tid = threadIdx.x;
    const int wave = tid >> 6, lane = tid & 63;
    const int lrow = lane & 15, lquad = lane >> 4;
    const int wr = (wave >> 1) * 64;
    const int wc = (wave & 1) * 32;

    const int stg_r = tid >> 3;
    const int stg_c = ((tid & 7) ^ ((tid >> 3) & 7)) * 8;
    const u16* gA = &X[(size_t)(m0 + stg_r) * 1024 + stg_c];
    const u16* gB = &WT[(size_t)(n0 + stg_r) * 1024 + stg_c];

    floatx4 acc[4][2];
#pragma unroll
    for (int mt = 0; mt < 4; mt++)
#pragma unroll
        for (int nt = 0; nt < 2; nt++) acc[mt][nt] = (floatx4){0.f, 0.f, 0.f, 0.f};

    GEMM_K_LOOP_N64();

#pragma unroll
    for (int mt = 0; mt < 4; mt++) {
        const int gm = m0 + wr + mt * 16 + lquad * 4;
#pragma unroll
        for (int nt = 0; nt < 2; nt++) {
            const int gn = n0 + wc + nt * 16 + lrow;
            const float bv = bias[gn];
#pragma unroll
            for (int i = 0; i < 4; i++)
                out[(size_t)(gm + i) * 1024 + gn] = acc[mt][nt][i] + bv;
        }
    }
}

// ---------------------------------------------------------------------------
extern "C" void kernel_launch(void* const* d_in, const int* in_sizes, int n_in,
                              void* d_out, int out_size, void* d_ws, size_t ws_size,
                              hipStream_t stream) {
    u16* ws = (u16*)d_ws + 64;

    const size_t MB1 = 1024 * 1024;
    u16* WT   = ws;              // 4 transposed weights (bf16)
    u16* Qw   = ws + 4 * MB1;    // [bh][2048][64], pre-scaled by 0.125*log2e
    u16* Kw   = ws + 8 * MB1;    // [bh][2048][64]
    u16* VTw  = ws + 12 * MB1;   // [bh][64][2048]
    u16* ctxw = ws + 16 * MB1;   // [4096][1024]
    u16* Xbf  = ws + 20 * MB1;   // x as bf16 [4096][1024]

    prep_kernel<<<dim3(32, 32, 5), dim3(32, 8), 0, stream>>>(
        (const float*)d_in[0], (const float*)d_in[1], (const float*)d_in[2],
        (const float*)d_in[3], (const float*)d_in[4], WT, Xbf);
    gemm_qkv_kernel<<<1536, 256, 0, stream>>>(Xbf, WT, Qw, Kw, VTw);
    attn_kernel<<<1024, 256, 0, stream>>>(Qw, Kw, VTw, ctxw);
    gemm_out_kernel<<<512, 256, 0, stream>>>(ctxw, WT + 3 * MB1, (const float*)d_in[5], (float*)d_out);
}